// Round 10
// baseline (298.280 us; speedup 1.0000x reference)
//
#include <hip/hip_runtime.h>
#include <hip/hip_bf16.h>

// B=64, T=2048, D=784, N1=100, N2=10, dt=0.04
// Pipeline:
//   prep_w16 : W1 -> fp16 2-way split (h, r*1024) in FRAGMENT ORDER for
//              mfma_f32_16x16x32_f16: image [kt=25][term 2][ct 7][lane 64][e 8]
//              (14336 B per K-tile, 358400 B total -> L2-resident per XCD)
//   gemm1_j  : z1 = batch @ W1^T, 3-term fp16 split on 16x16x32 MFMA (the
//              PROVEN shape/layout from rounds 6-7). NO LDS, NO BARRIERS:
//              B-fragments read directly from the L2-resident image
//              (coalesced base+lane*16), A global->reg 2-tile prefetch.
//              Waves fully independent -> HBM/L2/MFMA/VALU overlap freely.
//   fused_scan: scan1 + gemm2 + scan2 in one kernel (round-6/7 version verbatim).
//
// ws: Wg 358400 B | z1p 131072*100 f32 (52.4 MB)

#define FHN_DT 0.04f

typedef _Float16 f16x8 __attribute__((ext_vector_type(8)));
typedef __attribute__((ext_vector_type(4))) float f32x4;
typedef __attribute__((ext_vector_type(8))) unsigned short ushort8;

__device__ __forceinline__ void sync_lds() {
    asm volatile("s_waitcnt lgkmcnt(0)" ::: "memory");
    __builtin_amdgcn_s_barrier();
    asm volatile("" ::: "memory");
}

// ---------------- prep: W1 (100x784) -> fragment-order fp16 split image ----------------
// frag f = term*7 + ct ; short index = kt*7168 + f*512 + l*8 + e
// value: n = ct*16 + (l&15), k = kt*32 + (l>>4)*8 + e   (pad -> 0)
__global__ void prep_w16(const float* __restrict__ W1, unsigned short* __restrict__ Wg) {
    int idx = blockIdx.x * 256 + threadIdx.x;
    if (idx >= 179200) return;
    int kt   = idx / 7168;
    int rem  = idx % 7168;
    int f    = rem >> 9;
    int r2   = rem & 511;
    int l    = r2 >> 3;
    int e    = r2 & 7;
    int term = f / 7, ct = f % 7;
    int n = ct * 16 + (l & 15);
    int k = kt * 32 + (l >> 4) * 8 + e;
    float v = (n < 100 && k < 784) ? W1[n * 784 + k] : 0.0f;
    _Float16 h = (_Float16)v;
    unsigned short o;
    if (term == 0) o = __builtin_bit_cast(unsigned short, h);
    else           o = __builtin_bit_cast(unsigned short, (_Float16)((v - (float)h) * 1024.0f));
    Wg[idx] = o;
}

// ---------------- GEMM1: 3-term fp16 split on 16x16x32, BM=64, no LDS, no barriers ----------------
__global__ __launch_bounds__(256, 3) void gemm1_j(const float* __restrict__ A,
                                                  const unsigned short* __restrict__ Wg,
                                                  float* __restrict__ z1p) {
    const int tid  = threadIdx.x;
    const int w    = tid >> 6;
    const int lane = tid & 63;
    const int ln   = lane & 15;                     // output row-in-tile / C col sel
    const int kg   = lane >> 4;                     // k-slice = kg*8
    const long row0 = (long)blockIdx.x * 64;
    const float* aptr = A + (row0 + w * 16 + ln) * 784 + kg * 8;
    const char*  wgb  = (const char*)Wg + lane * 16;

    f32x4 acc1[7] = {};
    f32x4 acc2[7] = {};
    float afpA[8], afpB[8];

    // A: 8 floats/lane/tile (k = T*32 + kg*8 + 0..7). Tail T==24: kg>=2 would be
    // k>=784 -> clamp back 16 floats (re-reads kg-2 slice; W image is 0 there).
#define ISSUE_A(T, AF) {                                                        \
        const float* p_ = aptr + (T) * 32 - (((T) == 24 && kg >= 2) ? 16 : 0);  \
        *(float4*)&AF[0] = *(const float4*)(p_);                                \
        *(float4*)&AF[4] = *(const float4*)(p_ + 4); }

#define BODY(KT, AF) {                                                          \
        const char* wt_ = wgb + (size_t)(KT) * 14336;                           \
        ushort8 wf[14];                                                         \
        _Pragma("unroll")                                                       \
        for (int q_ = 0; q_ < 14; ++q_)                                         \
            wf[q_] = *(const ushort8*)(wt_ + q_ * 1024);                        \
        f16x8 ah, al;                                                           \
        _Pragma("unroll")                                                       \
        for (int e_ = 0; e_ < 8; ++e_) {                                        \
            float a_ = AF[e_];                                                  \
            _Float16 h_ = (_Float16)a_;                                         \
            ah[e_] = h_;                                                        \
            al[e_] = (_Float16)((a_ - (float)h_) * 1024.0f);                    \
        }                                                                       \
        if ((KT) < 23) ISSUE_A((KT) + 2, AF);                                   \
        _Pragma("unroll")                                                       \
        for (int ct_ = 0; ct_ < 7; ++ct_) {                                     \
            f16x8 bh = __builtin_bit_cast(f16x8, wf[ct_]);                      \
            f16x8 bl = __builtin_bit_cast(f16x8, wf[7 + ct_]);                  \
            acc1[ct_] = __builtin_amdgcn_mfma_f32_16x16x32_f16(ah, bh, acc1[ct_], 0, 0, 0); \
            acc2[ct_] = __builtin_amdgcn_mfma_f32_16x16x32_f16(ah, bl, acc2[ct_], 0, 0, 0); \
            acc2[ct_] = __builtin_amdgcn_mfma_f32_16x16x32_f16(al, bh, acc2[ct_], 0, 0, 0); \
        } }

    // prologue: A tiles 0,1 in flight
    ISSUE_A(0, afpA);
    ISSUE_A(1, afpB);

    for (int kt2 = 0; kt2 < 12; ++kt2) {
        BODY(kt2 * 2,     afpA);
        BODY(kt2 * 2 + 1, afpB);
    }
    BODY(24, afpA);

    // ---- epilogue: C/D map col = lane&15, row = kg*4 + r ; z = acc1 + acc2/1024 ----
#pragma unroll
    for (int ct = 0; ct < 7; ++ct) {
        int n = ct * 16 + ln;
        if (n < 100) {
            float* p = z1p + (row0 + w * 16 + kg * 4) * 100 + n;
#pragma unroll
            for (int r = 0; r < 4; ++r)
                p[r * 100] = fmaf(acc2[ct][r], 0.0009765625f, acc1[ct][r]);
        }
    }
#undef ISSUE_A
#undef BODY
}

// ---------------- fused scan1 + gemm2 + scan2 (round-6/7 version, unchanged) ----------------
__global__ __launch_bounds__(512) void fused_scan(const float* __restrict__ z1p,
                                                  const float* __restrict__ W2,
                                                  float* __restrict__ out) {
    __shared__ float fsm[32768];
    const int tid = threadIdx.x;
    const int b   = blockIdx.x;
    const float dt = FHN_DT;

    float V = 0.f, S = 0.f;
    const float* zb = z1p + (long)b * 2048 * 100 + tid;   // scan1 lanes only
    float z0[16], z1r[16], z2r[16], z3r[16];
    if (tid < 100) {
#pragma unroll
        for (int u = 0; u < 16; ++u) {
            z0[u]  = zb[u * 100];
            z1r[u] = zb[(16 + u) * 100];
            z2r[u] = zb[(32 + u) * 100];
            z3r[u] = zb[(48 + u) * 100];
        }
    }

    const int tg = tid - 128;
    int pp = tg >> 7;                                     // wave-uniform for tid>=128
    pp = __builtin_amdgcn_readfirstlane(pp);
    const int r  = tg & 127;
    const int mb = (pp == 0) ? 0 : (pp == 1 ? 4 : 7);
    const int mc = (pp == 0) ? 4 : 3;

    for (int i = 0; i <= 18; ++i) {
        if (tid < 128) {
            bool a1 = (tid < 100) && (i < 16);
            bool a2 = (tid >= 100) && (tid < 110) && (i >= 2) && (i < 18);
            if (a1 || a2) {
                const int cw = i & 1;
#pragma unroll
                for (int sub = 0; sub < 8; ++sub) {
                    float zt[16];
                    if (a1) {
                        int tn = (i * 8 + sub + 4) * 16;
                        if (tn < 2048) {
#pragma unroll
                            for (int u = 0; u < 16; ++u) zt[u] = zb[(tn + u) * 100];
                        }
                    }
                    if (a2) {
#pragma unroll
                        for (int u = 0; u < 16; ++u)
                            z0[u] = fsm[29696 + cw * 1536 + (sub * 16 + u) * 12 + (tid - 100)];
                    }
#pragma unroll
                    for (int u = 0; u < 16; ++u) {
                        int tl = sub * 16 + u;
                        fsm[cw * 14848 + tl * 116 + tid] = V;
                        float z  = z0[u];
                        float V3 = V * V * V;
                        float Vn = fmaf(1.f + dt, V,
                                    fmaf(-dt / 3.f, V3, fmaf(-dt, S, dt * z)));
                        float Sn = fmaf(dt * 0.08f, V + 0.7f - 0.8f * S, S);
                        V = Vn; S = Sn;
                    }
                    if (a1) {
#pragma unroll
                        for (int u = 0; u < 16; ++u) {
                            z0[u] = z1r[u]; z1r[u] = z2r[u]; z2r[u] = z3r[u]; z3r[u] = zt[u];
                        }
                    }
                }
            }
        } else {
            if (i >= 1 && i <= 16) {
                const int pb = (i - 1) & 1;
                float acc[4] = {0.f, 0.f, 0.f, 0.f};
                for (int kq = 0; kq < 25; ++kq) {
                    float4 v = *(const float4*)&fsm[pb * 14848 + r * 116 + kq * 4];
#pragma unroll
                    for (int j = 0; j < 4; ++j) {
                        if (j < mc) {
                            const float* wp = W2 + (mb + j) * 100 + kq * 4;  // uniform -> s_load
                            acc[j] = fmaf(v.x, wp[0], acc[j]);
                            acc[j] = fmaf(v.y, wp[1], acc[j]);
                            acc[j] = fmaf(v.z, wp[2], acc[j]);
                            acc[j] = fmaf(v.w, wp[3], acc[j]);
                        }
                    }
                }
#pragma unroll
                for (int j = 0; j < 4; ++j)
                    if (j < mc) fsm[29696 + pb * 1536 + r * 12 + mb + j] = 0.5f * acc[j];
            }
            if (i >= 3) {
                const int pb = (i - 1) & 1;
                float* dst = out + ((long)b * 2048 + (long)(i - 3) * 128 + r) * 10;
#pragma unroll
                for (int j = 0; j < 4; ++j)
                    if (j < mc) dst[mb + j] = fsm[pb * 14848 + r * 116 + 100 + mb + j];
            }
        }
        sync_lds();
    }
}

extern "C" void kernel_launch(void* const* d_in, const int* in_sizes, int n_in,
                              void* d_out, int out_size, void* d_ws, size_t ws_size,
                              hipStream_t stream) {
    const float* batch = (const float*)d_in[0];   // 64*2048*784
    const float* W1    = (const float*)d_in[1];   // 100*784
    const float* W2    = (const float*)d_in[2];   // 10*100
    float* out = (float*)d_out;                   // 64*2048*10

    char* base = (char*)d_ws;
    unsigned short* Wg = (unsigned short*)base;   // 358400 B
    float* z1p = (float*)(base + 358400);         // 131072*100 f32

    prep_w16<<<700, 256, 0, stream>>>(W1, Wg);
    gemm1_j<<<2048, 256, 0, stream>>>(batch, Wg, z1p);
    fused_scan<<<64, 512, 0, stream>>>(z1p, W2, out);
}

// Round 11
// 221.508 us; speedup vs baseline: 1.3466x; 1.3466x over previous
//
#include <hip/hip_runtime.h>
#include <hip/hip_bf16.h>

// B=64, T=2048, D=784, N1=100, N2=10, dt=0.04
// Pipeline:
//   prep_w3  : W1 -> fp16 2-way split (h, r*1024), per-K-tile image [25][2][112][40]
//              (round-6 version verbatim)
//   gemm1_n  : z1 = batch @ W1^T, 3-term fp16 split MFMA 16x16x32 (PROVEN layout).
//              Round-6 sync structure verbatim (split -> store -> prefetch ->
//              lgkm-only raw barrier -> compute), extended to rt=2 (BM=128):
//              each wave computes rows {w*32+ln, w*32+16+ln}; every B-fragment
//              ds_read_b128 feeds BOTH rows (halves LDS-read cost per output).
//              A per-lane global->reg double-buffered, 2-tile flight. Grid 1024.
//   fused_scan: scan1 + gemm2 + scan2 in one kernel (round-6/7 version verbatim).
//
// ws: Wg 448000 B | z1p 131072*100 f32 (52.4 MB)

#define FHN_DT 0.04f

typedef _Float16 f16x8 __attribute__((ext_vector_type(8)));
typedef __attribute__((ext_vector_type(4))) float          f32x4;
typedef __attribute__((ext_vector_type(8))) unsigned short ushort8;

__device__ __forceinline__ void sync_lds() {
    asm volatile("s_waitcnt lgkmcnt(0)" ::: "memory");
    __builtin_amdgcn_s_barrier();
    asm volatile("" ::: "memory");
}

// ---------------- prep: W1 (100x784) -> tiled fp16 2-term split image ----------------
// Image: [kt=25][term=2][n=112][40 shorts (32 data + 8 pad)]; term1 = (w-h)*1024
__global__ void prep_w3(const float* __restrict__ W1, unsigned short* __restrict__ Wg) {
    int idx = blockIdx.x * 256 + threadIdx.x;
    if (idx >= 224000) return;
    int sh    = idx % 40;
    int rest  = idx / 40;
    int n     = rest % 112;
    int rest2 = rest / 112;
    int term  = rest2 % 2;
    int kt    = rest2 / 2;
    int k = kt * 32 + sh;
    float v = (n < 100 && sh < 32 && k < 784) ? W1[n * 784 + k] : 0.0f;
    _Float16 h = (_Float16)v;
    _Float16 l = (_Float16)((v - (float)h) * 1024.0f);   // scale 2^10: no denormal flush
    Wg[idx] = (term == 0) ? __builtin_bit_cast(unsigned short, h)
                          : __builtin_bit_cast(unsigned short, l);
}

// ---------------- GEMM1: 3-term fp16 split, BM=128 (rt=2), BK=32, 4 waves ----------------
#define GW_TILE 8960     // shorts per K-tile (2 terms x 112 x 40)

__global__ __launch_bounds__(256, 2) void gemm1_n(const float* __restrict__ A,
                                                  const unsigned short* __restrict__ Wg,
                                                  float* __restrict__ z1p) {
    __shared__ __align__(16) unsigned short Wl[2][GW_TILE];   // 35840 B
    const int tid  = threadIdx.x;
    const int w    = tid >> 6;
    const int lane = tid & 63;
    const int ln   = lane & 15;
    const int kg   = lane >> 4;                  // k-slice = kg*8
    const long row0 = (long)blockIdx.x * 128;

    // two A rows per lane: w*32 + ln and w*32 + 16 + ln
    const float* arow0 = A + (row0 + w * 32 + ln) * 784 + kg * 8;
    const float* arow1 = arow0 + (size_t)16 * 784;

    f32x4 acc1[2][7] = {};
    f32x4 acc2[2][7] = {};
    float afpA[16], afpB[16];       // [0..7] row0, [8..15] row1
    ushort8 wreg[5];

    // A tile T into AF (k = T*32 + kg*8 + 0..7); T==24 & kg>=2 -> k>=784: zeros
#define ISSUE_A(T, AF) {                                                        \
        if ((T) == 24 && kg >= 2) {                                             \
            *(float4*)&AF[0]  = make_float4(0.f, 0.f, 0.f, 0.f);                \
            *(float4*)&AF[4]  = make_float4(0.f, 0.f, 0.f, 0.f);                \
            *(float4*)&AF[8]  = make_float4(0.f, 0.f, 0.f, 0.f);                \
            *(float4*)&AF[12] = make_float4(0.f, 0.f, 0.f, 0.f);                \
        } else {                                                                \
            *(float4*)&AF[0]  = *(const float4*)(arow0 + (T) * 32);             \
            *(float4*)&AF[4]  = *(const float4*)(arow0 + (T) * 32 + 4);         \
            *(float4*)&AF[8]  = *(const float4*)(arow1 + (T) * 32);             \
            *(float4*)&AF[12] = *(const float4*)(arow1 + (T) * 32 + 4);         \
        } }

#define LOADW(T) {                                                              \
        _Pragma("unroll")                                                       \
        for (int j_ = 0; j_ < 5; ++j_) {                                        \
            int off_ = j_ * 4096 + tid * 16;                                    \
            if (off_ < 17920)                                                   \
                wreg[j_] = *(const ushort8*)((const char*)Wg                    \
                            + (size_t)(T) * 17920 + off_);                      \
        } }

#define BODY(KT, AF) {                                                          \
        /* 1. split A (consumes AF -> compiler waits its vmem) */               \
        f16x8 ah0, al0, ah1, al1;                                               \
        _Pragma("unroll")                                                       \
        for (int e_ = 0; e_ < 8; ++e_) {                                        \
            float a0_ = AF[e_], a1_ = AF[8 + e_];                               \
            _Float16 h0_ = (_Float16)a0_, h1_ = (_Float16)a1_;                  \
            ah0[e_] = h0_; ah1[e_] = h1_;                                       \
            al0[e_] = (_Float16)((a0_ - (float)h0_) * 1024.0f);                 \
            al1[e_] = (_Float16)((a1_ - (float)h1_) * 1024.0f);                 \
        }                                                                       \
        /* 2. store W tile KT (consumes wreg -> compiler waits its vmem) */     \
        {                                                                       \
            unsigned short* buf_ = &Wl[(KT) & 1][0];                            \
            _Pragma("unroll")                                                   \
            for (int j_ = 0; j_ < 5; ++j_) {                                    \
                int off_ = j_ * 4096 + tid * 16;                                \
                if (off_ < 17920) *(ushort8*)((char*)buf_ + off_) = wreg[j_];   \
            }                                                                   \
        }                                                                       \
        /* 3. prefetch next tiles (fly across barrier + compute) */             \
        if ((KT) < 24) LOADW((KT) + 1);                                         \
        if ((KT) < 23) ISSUE_A((KT) + 2, AF);                                   \
        /* 4. barrier: lgkmcnt only; vmem stays in flight */                    \
        sync_lds();                                                             \
        /* 5. compute: 7 ct, B-frags read ONCE, used for both rows */           \
        const unsigned short* cb_ = &Wl[(KT) & 1][0];                           \
        _Pragma("unroll")                                                       \
        for (int ct_ = 0; ct_ < 7; ++ct_) {                                     \
            const unsigned short* pw_ = cb_ + (ct_ * 16 + ln) * 40 + kg * 8;    \
            f16x8 bh = *(const f16x8*)(pw_);                                    \
            f16x8 bl = *(const f16x8*)(pw_ + 4480);                             \
            acc1[0][ct_] = __builtin_amdgcn_mfma_f32_16x16x32_f16(ah0, bh, acc1[0][ct_], 0, 0, 0); \
            acc2[0][ct_] = __builtin_amdgcn_mfma_f32_16x16x32_f16(ah0, bl, acc2[0][ct_], 0, 0, 0); \
            acc2[0][ct_] = __builtin_amdgcn_mfma_f32_16x16x32_f16(al0, bh, acc2[0][ct_], 0, 0, 0); \
            acc1[1][ct_] = __builtin_amdgcn_mfma_f32_16x16x32_f16(ah1, bh, acc1[1][ct_], 0, 0, 0); \
            acc2[1][ct_] = __builtin_amdgcn_mfma_f32_16x16x32_f16(ah1, bl, acc2[1][ct_], 0, 0, 0); \
            acc2[1][ct_] = __builtin_amdgcn_mfma_f32_16x16x32_f16(al1, bh, acc2[1][ct_], 0, 0, 0); \
        } }

    // prologue: W(0) + A(0) + A(1) into regs (first waits happen inside BODY(0))
    LOADW(0);
    ISSUE_A(0, afpA);
    ISSUE_A(1, afpB);

    for (int kt2 = 0; kt2 < 12; ++kt2) {
        BODY(kt2 * 2,     afpA);
        BODY(kt2 * 2 + 1, afpB);
    }
    BODY(24, afpA);

    // ---- epilogue: C/D map col = lane&15, row = kg*4 + r ; z = acc1 + acc2/1024 ----
#pragma unroll
    for (int ct = 0; ct < 7; ++ct) {
        int n = ct * 16 + ln;
        if (n < 100) {
#pragma unroll
            for (int rt = 0; rt < 2; ++rt) {
                long rg = row0 + w * 32 + rt * 16 + kg * 4;
                float* p = z1p + rg * 100 + n;
#pragma unroll
                for (int r = 0; r < 4; ++r)
                    p[r * 100] = fmaf(acc2[rt][ct][r], 0.0009765625f, acc1[rt][ct][r]);
            }
        }
    }
#undef ISSUE_A
#undef LOADW
#undef BODY
}

// ---------------- fused scan1 + gemm2 + scan2 (round-6/7 version, unchanged) ----------------
__global__ __launch_bounds__(512) void fused_scan(const float* __restrict__ z1p,
                                                  const float* __restrict__ W2,
                                                  float* __restrict__ out) {
    __shared__ float fsm[32768];
    const int tid = threadIdx.x;
    const int b   = blockIdx.x;
    const float dt = FHN_DT;

    float V = 0.f, S = 0.f;
    const float* zb = z1p + (long)b * 2048 * 100 + tid;   // scan1 lanes only
    float z0[16], z1r[16], z2r[16], z3r[16];
    if (tid < 100) {
#pragma unroll
        for (int u = 0; u < 16; ++u) {
            z0[u]  = zb[u * 100];
            z1r[u] = zb[(16 + u) * 100];
            z2r[u] = zb[(32 + u) * 100];
            z3r[u] = zb[(48 + u) * 100];
        }
    }

    const int tg = tid - 128;
    int pp = tg >> 7;                                     // wave-uniform for tid>=128
    pp = __builtin_amdgcn_readfirstlane(pp);
    const int r  = tg & 127;
    const int mb = (pp == 0) ? 0 : (pp == 1 ? 4 : 7);
    const int mc = (pp == 0) ? 4 : 3;

    for (int i = 0; i <= 18; ++i) {
        if (tid < 128) {
            bool a1 = (tid < 100) && (i < 16);
            bool a2 = (tid >= 100) && (tid < 110) && (i >= 2) && (i < 18);
            if (a1 || a2) {
                const int cw = i & 1;
#pragma unroll
                for (int sub = 0; sub < 8; ++sub) {
                    float zt[16];
                    if (a1) {
                        int tn = (i * 8 + sub + 4) * 16;
                        if (tn < 2048) {
#pragma unroll
                            for (int u = 0; u < 16; ++u) zt[u] = zb[(tn + u) * 100];
                        }
                    }
                    if (a2) {
#pragma unroll
                        for (int u = 0; u < 16; ++u)
                            z0[u] = fsm[29696 + cw * 1536 + (sub * 16 + u) * 12 + (tid - 100)];
                    }
#pragma unroll
                    for (int u = 0; u < 16; ++u) {
                        int tl = sub * 16 + u;
                        fsm[cw * 14848 + tl * 116 + tid] = V;
                        float z  = z0[u];
                        float V3 = V * V * V;
                        float Vn = fmaf(1.f + dt, V,
                                    fmaf(-dt / 3.f, V3, fmaf(-dt, S, dt * z)));
                        float Sn = fmaf(dt * 0.08f, V + 0.7f - 0.8f * S, S);
                        V = Vn; S = Sn;
                    }
                    if (a1) {
#pragma unroll
                        for (int u = 0; u < 16; ++u) {
                            z0[u] = z1r[u]; z1r[u] = z2r[u]; z2r[u] = z3r[u]; z3r[u] = zt[u];
                        }
                    }
                }
            }
        } else {
            if (i >= 1 && i <= 16) {
                const int pb = (i - 1) & 1;
                float acc[4] = {0.f, 0.f, 0.f, 0.f};
                for (int kq = 0; kq < 25; ++kq) {
                    float4 v = *(const float4*)&fsm[pb * 14848 + r * 116 + kq * 4];
#pragma unroll
                    for (int j = 0; j < 4; ++j) {
                        if (j < mc) {
                            const float* wp = W2 + (mb + j) * 100 + kq * 4;  // uniform -> s_load
                            acc[j] = fmaf(v.x, wp[0], acc[j]);
                            acc[j] = fmaf(v.y, wp[1], acc[j]);
                            acc[j] = fmaf(v.z, wp[2], acc[j]);
                            acc[j] = fmaf(v.w, wp[3], acc[j]);
                        }
                    }
                }
#pragma unroll
                for (int j = 0; j < 4; ++j)
                    if (j < mc) fsm[29696 + pb * 1536 + r * 12 + mb + j] = 0.5f * acc[j];
            }
            if (i >= 3) {
                const int pb = (i - 1) & 1;
                float* dst = out + ((long)b * 2048 + (long)(i - 3) * 128 + r) * 10;
#pragma unroll
                for (int j = 0; j < 4; ++j)
                    if (j < mc) dst[mb + j] = fsm[pb * 14848 + r * 116 + 100 + mb + j];
            }
        }
        sync_lds();
    }
}

extern "C" void kernel_launch(void* const* d_in, const int* in_sizes, int n_in,
                              void* d_out, int out_size, void* d_ws, size_t ws_size,
                              hipStream_t stream) {
    const float* batch = (const float*)d_in[0];   // 64*2048*784
    const float* W1    = (const float*)d_in[1];   // 100*784
    const float* W2    = (const float*)d_in[2];   // 10*100
    float* out = (float*)d_out;                   // 64*2048*10

    char* base = (char*)d_ws;
    unsigned short* Wg = (unsigned short*)base;   // 448000 B
    float* z1p = (float*)(base + 448000);         // 131072*100 f32

    prep_w3<<<875, 256, 0, stream>>>(W1, Wg);
    gemm1_n<<<1024, 256, 0, stream>>>(batch, Wg, z1p);
    fused_scan<<<64, 512, 0, stream>>>(z1p, W2, out);
}